// Round 12
// baseline (44.318 us; speedup 1.0000x reference)
//
#include <hip/hip_runtime.h>
#include <math.h>

// Problem constants (from reference setup_inputs)
#define BB   32    // batch
#define CC   256   // channels
#define HF   64    // feature H
#define WF   64    // feature W
#define NN   256   // grid points (16x16, step 4)
#define MROWS 32   // rows per sim strip
#define NSTRIP (NN / MROWS)  // 8 strips per batch
#define SIMP 260   // padded sim row stride (floats)
#define NXCD 8
#define SIMBLOCKS (BB * NSTRIP)   // 256

typedef __attribute__((ext_vector_type(8))) short    bf16x8;
typedef __attribute__((ext_vector_type(4))) float    f32x4;
typedef __attribute__((ext_vector_type(8))) unsigned short u16x8;

__device__ inline unsigned short f2bf(float f) {   // round-to-nearest-even
    unsigned u = __float_as_uint(f);
    unsigned r = u + 0x7FFFu + ((u >> 16) & 1u);
    return (unsigned short)(r >> 16);
}

// ---------------------------------------------------------------------------
// Kernel A (R11-exact + accumulator init): block = (b, grid-row i).
// Coalesced float4 row loads (keep .x), LDS transpose, f32 sumsq partials,
// coalesced bf16 n-major stores. Block 0 zero-inits doneCnt/lossB/corrB
// (kernel-boundary coherence makes this visible to kernel B's atomics).
// XCD-swizzled to match sim (XCD x owns batches 4x..4x+3).
// ---------------------------------------------------------------------------
__global__ __launch_bounds__(256) void gather_kernel(
        const float* __restrict__ fr,
        const float* __restrict__ fd,
        const float* __restrict__ vm,
        unsigned short* __restrict__ Dbf,
        unsigned short* __restrict__ Rbf,
        float* __restrict__ nPartD,
        float* __restrict__ nPartR,
        float* __restrict__ GV,
        float* __restrict__ lossB,
        float* __restrict__ corrB,
        unsigned int* __restrict__ doneCnt) {
    __shared__ float ldsD[16][257];   // [j][c], +1 pad
    __shared__ float ldsR[16][257];

    int blk = blockIdx.x;             // 512 blocks
    int xcd = blk & (NXCD - 1);
    int r   = blk >> 3;
    int b   = xcd * 4 + (r & 3);
    int i   = r >> 2;                 // grid row 0..15
    int t   = threadIdx.x;
    int g   = t >> 4;                 // channel subgroup 0..15
    int k   = t & 15;                 // point index / float4 slot

    if (blk == 0) {
        if (t < BB) { lossB[t] = 0.0f; corrB[t] = 0.0f; }
        if (t == 0) *doneCnt = 0u;
    }

    // depth map: 16 iterations, channel c = it*16 + g
#pragma unroll
    for (int it = 0; it < 16; ++it) {
        int c = it * 16 + g;
        const float4* row = reinterpret_cast<const float4*>(
            fd + ((size_t)(b * CC + c) * HF + 4 * i) * WF);
        float4 v = row[k];            // coalesced 16B; .x = point x=4k
        ldsD[k][c] = v.x;
    }
    // rgb map
#pragma unroll
    for (int it = 0; it < 16; ++it) {
        int c = it * 16 + g;
        const float4* row = reinterpret_cast<const float4*>(
            fr + ((size_t)(b * CC + c) * HF + 4 * i) * WF);
        float4 v = row[k];
        ldsR[k][c] = v.x;
    }
    __syncthreads();

    int j = t >> 4, p = t & 15;       // output point j, channel chunk p
    float ssd = 0.0f, ssr = 0.0f;
    unsigned short db[16], rb[16];
#pragma unroll
    for (int q = 0; q < 16; ++q) {
        float a  = ldsD[j][p * 16 + q];
        float c2 = ldsR[j][p * 16 + q];
        db[q] = f2bf(a);
        rb[q] = f2bf(c2);
        ssd = fmaf(a, a, ssd);
        ssr = fmaf(c2, c2, ssr);
    }
    int n = i * 16 + j;
    nPartD[(size_t)(b * 16 + p) * NN + n] = ssd;
    nPartR[(size_t)(b * 16 + p) * NN + n] = ssr;

    unsigned short* dDst = Dbf + ((size_t)(b * NN + n) * CC + p * 16);
    unsigned short* rDst = Rbf + ((size_t)(b * NN + n) * CC + p * 16);
    *reinterpret_cast<u16x8*>(dDst)     = *reinterpret_cast<u16x8*>(&db[0]);
    *reinterpret_cast<u16x8*>(dDst + 8) = *reinterpret_cast<u16x8*>(&db[8]);
    *reinterpret_cast<u16x8*>(rDst)     = *reinterpret_cast<u16x8*>(&rb[0]);
    *reinterpret_cast<u16x8*>(rDst + 8) = *reinterpret_cast<u16x8*>(&rb[8]);

    if (t < 16) {
        float v = vm[((size_t)b * 512 + 32 * i) * 512 + 32 * t];
        GV[(size_t)b * NN + i * 16 + t] = (v > 0.5f) ? 1.0f : 0.0f;
    }
}

// ---------------------------------------------------------------------------
// Kernel B: MFMA sim (R6-verbatim core) + atomic-fused finalize.
// Per-block partials go through device-scope f32 atomicAdd (coherent point,
// NO threadfence). A single s_waitcnt vmcnt(0) orders the partial-adds
// before the doneCnt increment; atomic RMW global ordering then guarantees
// the last block (old==SIMBLOCKS-1) sees all partials via atomic reads.
// ---------------------------------------------------------------------------
__global__ __launch_bounds__(256) void sim_loss_kernel(
        const unsigned short* __restrict__ Dbf,
        const unsigned short* __restrict__ Rbf,
        const float* __restrict__ nPartD,
        const float* __restrict__ nPartR,
        const float* __restrict__ GV,
        float* __restrict__ lossB,
        float* __restrict__ corrB,
        unsigned int* __restrict__ doneCnt,
        float* __restrict__ out) {
    __shared__ float simLds[MROWS * SIMP];   // 33.3 KB
    __shared__ float colInv[NN];
    __shared__ float validF[NN];
    __shared__ float rowInv[MROWS];
    __shared__ float diagLds[MROWS];
    __shared__ float rowLoss[MROWS];
    __shared__ float rowCorr[MROWS];
    __shared__ int   lastFlag;
    __shared__ float sl[BB], sc2[BB], st2[BB];

    int blk   = blockIdx.x;                  // 256 blocks
    int xcd   = blk & (NXCD - 1);
    int rr    = blk >> 3;
    int b     = xcd * 4 + (rr & 3);
    int strip = rr >> 2;
    int nbase = strip * MROWS;

    int t  = threadIdx.x;
    int w  = t >> 6;
    int l  = t & 63;
    int lg = l >> 4, lr = l & 15;

    // ---- norms + validity into LDS ----
    {
        float ss = 0.0f;
#pragma unroll
        for (int p = 0; p < 16; ++p) ss += nPartR[(size_t)(b * 16 + p) * NN + t];
        colInv[t] = 1.0f / fmaxf(sqrtf(ss), 1e-12f);
        validF[t] = GV[(size_t)b * NN + t];
    }
    if (t < MROWS) {
        float ss = 0.0f;
#pragma unroll
        for (int p = 0; p < 16; ++p) ss += nPartD[(size_t)(b * 16 + p) * NN + nbase + t];
        rowInv[t] = 1.0f / fmaxf(sqrtf(ss), 1e-12f);
    }
    __syncthreads();

    // ---- MFMA GEMM ----
    const unsigned short* Dp = Dbf + (size_t)(b * NN + nbase) * CC;
    const unsigned short* Rp = Rbf + (size_t)b * NN * CC;

    f32x4 acc[2][4] = {};

#pragma unroll
    for (int ks = 0; ks < 8; ++ks) {
        int coff = ks * 32 + lg * 8;
        bf16x8 a0 = *reinterpret_cast<const bf16x8*>(Dp + (size_t)(lr)      * CC + coff);
        bf16x8 a1 = *reinterpret_cast<const bf16x8*>(Dp + (size_t)(16 + lr) * CC + coff);
        bf16x8 b0 = *reinterpret_cast<const bf16x8*>(Rp + (size_t)(w * 64 +  0 + lr) * CC + coff);
        bf16x8 b1 = *reinterpret_cast<const bf16x8*>(Rp + (size_t)(w * 64 + 16 + lr) * CC + coff);
        bf16x8 b2 = *reinterpret_cast<const bf16x8*>(Rp + (size_t)(w * 64 + 32 + lr) * CC + coff);
        bf16x8 b3 = *reinterpret_cast<const bf16x8*>(Rp + (size_t)(w * 64 + 48 + lr) * CC + coff);
        acc[0][0] = __builtin_amdgcn_mfma_f32_16x16x32_bf16(a0, b0, acc[0][0], 0, 0, 0);
        acc[0][1] = __builtin_amdgcn_mfma_f32_16x16x32_bf16(a0, b1, acc[0][1], 0, 0, 0);
        acc[0][2] = __builtin_amdgcn_mfma_f32_16x16x32_bf16(a0, b2, acc[0][2], 0, 0, 0);
        acc[0][3] = __builtin_amdgcn_mfma_f32_16x16x32_bf16(a0, b3, acc[0][3], 0, 0, 0);
        acc[1][0] = __builtin_amdgcn_mfma_f32_16x16x32_bf16(a1, b0, acc[1][0], 0, 0, 0);
        acc[1][1] = __builtin_amdgcn_mfma_f32_16x16x32_bf16(a1, b1, acc[1][1], 0, 0, 0);
        acc[1][2] = __builtin_amdgcn_mfma_f32_16x16x32_bf16(a1, b2, acc[1][2], 0, 0, 0);
        acc[1][3] = __builtin_amdgcn_mfma_f32_16x16x32_bf16(a1, b3, acc[1][3], 0, 0, 0);
    }

    // ---- epilogue: scale, diag capture, mask, store rows to LDS ----
    const float invT = 1.0f / 0.07f;
#pragma unroll
    for (int mi = 0; mi < 2; ++mi) {
#pragma unroll
        for (int ni = 0; ni < 4; ++ni) {
            int col = w * 64 + ni * 16 + lr;
            float ci = colInv[col];
            float gv = validF[col];
#pragma unroll
            for (int reg = 0; reg < 4; ++reg) {
                int lrow = mi * 16 + lg * 4 + reg;
                float s = acc[mi][ni][reg] * invT * rowInv[lrow] * ci;
                if (col == nbase + lrow) diagLds[lrow] = s;
                simLds[lrow * SIMP + col] = (gv > 0.5f) ? s : -1e30f;
            }
        }
    }
    __syncthreads();

    // ---- one wave per row: max/argmax + sum-exp via shfl only ----
    for (int k = w; k < MROWS; k += 4) {
        const float* row = &simLds[k * SIMP];
        float v0 = row[l];
        float v1 = row[64 + l];
        float v2 = row[128 + l];
        float v3 = row[192 + l];
        float mv = v0; int mi = l;
        if (v1 > mv) { mv = v1; mi = l + 64; }
        if (v2 > mv) { mv = v2; mi = l + 128; }
        if (v3 > mv) { mv = v3; mi = l + 192; }
#pragma unroll
        for (int off = 32; off > 0; off >>= 1) {
            float ov = __shfl_xor(mv, off, 64);
            int   oi = __shfl_xor(mi, off, 64);
            if (ov > mv || (ov == mv && oi < mi)) { mv = ov; mi = oi; }
        }
        float e = __expf(v0 - mv) + __expf(v1 - mv) + __expf(v2 - mv) + __expf(v3 - mv);
#pragma unroll
        for (int off = 32; off > 0; off >>= 1) e += __shfl_xor(e, off, 64);
        if (l == 0) {
            float vfn = validF[nbase + k];
            float lz = mv + __logf(e);
            rowLoss[k] = (vfn > 0.5f) ? (lz - diagLds[k]) : 0.0f;
            rowCorr[k] = (vfn > 0.5f && mi == nbase + k) ? 1.0f : 0.0f;
        }
    }
    __syncthreads();

    if (t == 0) {
        float la = 0.0f, ca = 0.0f;
#pragma unroll
        for (int k = 0; k < MROWS; ++k) { la += rowLoss[k]; ca += rowCorr[k]; }
        atomicAdd(&lossB[b], la);                 // device-coherent point
        atomicAdd(&corrB[b], ca);
        asm volatile("s_waitcnt vmcnt(0)" ::: "memory");  // adds complete
        unsigned old = atomicAdd(doneCnt, 1u);    // globally ordered RMW
        lastFlag = (old == SIMBLOCKS - 1) ? 1 : 0;
    }
    __syncthreads();

    // ---- fused finalize: only the last-done block runs this ----
    if (lastFlag) {
        int bb = t >> 3, s = t & 7;

        float nvp = 0.0f;
        const float4* g4 = reinterpret_cast<const float4*>(GV + (size_t)bb * NN);
#pragma unroll
        for (int q = 0; q < 8; ++q) {
            float4 v = g4[s * 8 + q];
            nvp += v.x + v.y + v.z + v.w;
        }
#pragma unroll
        for (int off = 1; off < 8; off <<= 1) nvp += __shfl_xor(nvp, off, 64);

        if (s == 0) {
            // coherent reads of the atomic accumulators
            float lb = atomicAdd(&lossB[bb], 0.0f);
            float cb = atomicAdd(&corrB[bb], 0.0f);
            bool inc = (nvp >= 2.0f);
            sl[bb]  = inc ? (lb / fmaxf(nvp, 1.0f)) : 0.0f;
            sc2[bb] = inc ? cb : 0.0f;
            st2[bb] = inc ? nvp : 0.0f;
        }
        __syncthreads();
        if (t == 0) {
            float L = 0.0f, Ccnt = 0.0f, Tcnt = 0.0f;
            for (int q = 0; q < BB; ++q) { L += sl[q]; Ccnt += sc2[q]; Tcnt += st2[q]; }
            float avg = L / (float)BB;
            out[0] = (Tcnt > 0.0f) ? avg : 0.0f;
            out[1] = (Tcnt > 0.0f) ? (Ccnt / fmaxf(Tcnt, 1.0f) * 100.0f) : 0.0f;
        }
    }
}

extern "C" void kernel_launch(void* const* d_in, const int* in_sizes, int n_in,
                              void* d_out, int out_size, void* d_ws, size_t ws_size,
                              hipStream_t stream) {
    const float* fr = (const float*)d_in[0];  // fmap_rgb
    const float* fd = (const float*)d_in[1];  // fmap_depth
    // d_in[2] = projected_coords: DEAD in reference (_rgb_pos never used)
    const float* vm = (const float*)d_in[3];  // valid_mask

    float* out = (float*)d_out;
    char* ws = (char*)d_ws;

    // Workspace layout (~9.1 MB total)
    size_t featBytes = (size_t)BB * NN * CC * 2;        // 4 MB each (bf16)
    size_t partBytes = (size_t)BB * 16 * NN * 4;        // 512 KB each
    unsigned short* Dbf = (unsigned short*)ws;
    unsigned short* Rbf = (unsigned short*)(ws + featBytes);
    float* nPartD   = (float*)(ws + 2 * featBytes);
    float* nPartR   = (float*)(ws + 2 * featBytes + partBytes);
    float* GV       = (float*)(ws + 2 * featBytes + 2 * partBytes);
    float* lossB    = GV + (size_t)BB * NN;             // BB
    float* corrB    = lossB + BB;                       // BB
    unsigned int* doneCnt = (unsigned int*)(corrB + BB);

    hipLaunchKernelGGL(gather_kernel, dim3(BB * 16), dim3(256), 0, stream,
                       fr, fd, vm, Dbf, Rbf, nPartD, nPartR, GV,
                       lossB, corrB, doneCnt);
    hipLaunchKernelGGL(sim_loss_kernel, dim3(SIMBLOCKS), dim3(256), 0, stream,
                       Dbf, Rbf, nPartD, nPartR, GV, lossB, corrB,
                       doneCnt, out);
}

// Round 13
// 38.064 us; speedup vs baseline: 1.1643x; 1.1643x over previous
//
#include <hip/hip_runtime.h>
#include <math.h>

// Problem constants (from reference setup_inputs)
#define BB   32    // batch
#define CC   256   // channels
#define HF   64    // feature H
#define WF   64    // feature W
#define NN   256   // grid points (16x16, step 4)
#define MROWS 32   // rows per sim block (strip)
#define NSTRIP (NN / MROWS)  // 8 strips per batch
#define SIMP 260   // padded sim row stride (floats)
#define NXCD 8

typedef __attribute__((ext_vector_type(8))) short    bf16x8;
typedef __attribute__((ext_vector_type(4))) float    f32x4;
typedef __attribute__((ext_vector_type(8))) unsigned short u16x8;

__device__ inline unsigned short f2bf(float f) {   // round-to-nearest-even
    unsigned u = __float_as_uint(f);
    unsigned r = u + 0x7FFFu + ((u >> 16) & 1u);
    return (unsigned short)(r >> 16);
}

// ---------------------------------------------------------------------------
// Kernel A: coalesced gather -> bf16 features (n-major) + f32 norm partials.
//   Dbf/Rbf[b][n][c]  (bf16, one grid point's 256 channels = 512 B rows)
//   nPartD/nPartR[b][cg][n]  (f32 sumsq over 16-channel group cg)
//   GV[b][n]  (grid_valid 0/1) -- cg==0 blocks only
// XCD-swizzled to match sim's placement (XCD x owns batches 4x..4x+3).
// (R6-exact: the best-measured 38.7 us configuration.)
// ---------------------------------------------------------------------------
__global__ __launch_bounds__(256) void gather_kernel(
        const float* __restrict__ fr,
        const float* __restrict__ fd,
        const float* __restrict__ vm,
        unsigned short* __restrict__ Dbf,
        unsigned short* __restrict__ Rbf,
        float* __restrict__ nPartD,
        float* __restrict__ nPartR,
        float* __restrict__ GV) {
    int blk = blockIdx.x;
    int xcd = blk & (NXCD - 1);
    int r   = blk >> 3;
    int b   = xcd * 4 + (r & 3);
    int cg  = r >> 2;

    int t = threadIdx.x;
    int i = t >> 4, j = t & 15;           // grid point (i,j) -> (y,x)=(4i,4j)

    size_t mapBase = (size_t)(b * CC + cg * 16) * (HF * WF);
    size_t ptOff   = (size_t)(4 * i) * WF + 4 * j;

    float ssd = 0.0f, ssr = 0.0f;
    unsigned short dbuf[16], rbuf[16];
#pragma unroll
    for (int cc = 0; cc < 16; ++cc) {
        float vd_ = fd[mapBase + (size_t)cc * (HF * WF) + ptOff];
        float vr_ = fr[mapBase + (size_t)cc * (HF * WF) + ptOff];
        dbuf[cc] = f2bf(vd_);
        rbuf[cc] = f2bf(vr_);
        ssd = fmaf(vd_, vd_, ssd);
        ssr = fmaf(vr_, vr_, ssr);
    }
    unsigned short* dDst = Dbf + ((size_t)(b * NN + t) * CC + cg * 16);
    unsigned short* rDst = Rbf + ((size_t)(b * NN + t) * CC + cg * 16);
    *reinterpret_cast<u16x8*>(dDst)     = *reinterpret_cast<u16x8*>(&dbuf[0]);
    *reinterpret_cast<u16x8*>(dDst + 8) = *reinterpret_cast<u16x8*>(&dbuf[8]);
    *reinterpret_cast<u16x8*>(rDst)     = *reinterpret_cast<u16x8*>(&rbuf[0]);
    *reinterpret_cast<u16x8*>(rDst + 8) = *reinterpret_cast<u16x8*>(&rbuf[8]);

    nPartD[(size_t)(b * 16 + cg) * NN + t] = ssd;
    nPartR[(size_t)(b * 16 + cg) * NN + t] = ssr;

    if (cg == 0) {
        float v = vm[((size_t)b * 512 + 32 * i) * 512 + 32 * j];
        GV[(size_t)b * NN + t] = (v > 0.5f) ? 1.0f : 0.0f;
    }
}

// ---------------------------------------------------------------------------
// Kernel B: MFMA sim (R6-exact). Block = (b, 32-row strip), 256 blocks,
// 4 waves. Wave w: rows [nbase,+32) x cols [w*64,+64) via 2(M)x4(N)
// mfma_f32_16x16x32_bf16, 8 K-steps.
// C/D layout (m89): col = lane&15, row = (lane>>4)*4 + reg.
// ---------------------------------------------------------------------------
__global__ __launch_bounds__(256) void sim_loss_kernel(
        const unsigned short* __restrict__ Dbf,
        const unsigned short* __restrict__ Rbf,
        const float* __restrict__ nPartD,
        const float* __restrict__ nPartR,
        const float* __restrict__ GV,
        float* __restrict__ lossPart,
        float* __restrict__ corrPart) {
    __shared__ float simLds[MROWS * SIMP];   // 33.3 KB
    __shared__ float colInv[NN];
    __shared__ float validF[NN];
    __shared__ float rowInv[MROWS];
    __shared__ float diagLds[MROWS];
    __shared__ float rowLoss[MROWS];
    __shared__ float rowCorr[MROWS];

    int blk   = blockIdx.x;                  // 256 blocks
    int xcd   = blk & (NXCD - 1);
    int rr    = blk >> 3;
    int b     = xcd * 4 + (rr & 3);
    int strip = rr >> 2;
    int nbase = strip * MROWS;

    int t  = threadIdx.x;
    int w  = t >> 6;
    int l  = t & 63;
    int lg = l >> 4, lr = l & 15;

    // ---- norms + validity into LDS ----
    {
        float ss = 0.0f;
#pragma unroll
        for (int p = 0; p < 16; ++p) ss += nPartR[(size_t)(b * 16 + p) * NN + t];
        colInv[t] = 1.0f / fmaxf(sqrtf(ss), 1e-12f);
        validF[t] = GV[(size_t)b * NN + t];
    }
    if (t < MROWS) {
        float ss = 0.0f;
#pragma unroll
        for (int p = 0; p < 16; ++p) ss += nPartD[(size_t)(b * 16 + p) * NN + nbase + t];
        rowInv[t] = 1.0f / fmaxf(sqrtf(ss), 1e-12f);
    }
    __syncthreads();

    // ---- MFMA GEMM ----
    const unsigned short* Dp = Dbf + (size_t)(b * NN + nbase) * CC;
    const unsigned short* Rp = Rbf + (size_t)b * NN * CC;

    f32x4 acc[2][4] = {};

#pragma unroll
    for (int ks = 0; ks < 8; ++ks) {
        int coff = ks * 32 + lg * 8;
        bf16x8 a0 = *reinterpret_cast<const bf16x8*>(Dp + (size_t)(lr)      * CC + coff);
        bf16x8 a1 = *reinterpret_cast<const bf16x8*>(Dp + (size_t)(16 + lr) * CC + coff);
        bf16x8 b0 = *reinterpret_cast<const bf16x8*>(Rp + (size_t)(w * 64 +  0 + lr) * CC + coff);
        bf16x8 b1 = *reinterpret_cast<const bf16x8*>(Rp + (size_t)(w * 64 + 16 + lr) * CC + coff);
        bf16x8 b2 = *reinterpret_cast<const bf16x8*>(Rp + (size_t)(w * 64 + 32 + lr) * CC + coff);
        bf16x8 b3 = *reinterpret_cast<const bf16x8*>(Rp + (size_t)(w * 64 + 48 + lr) * CC + coff);
        acc[0][0] = __builtin_amdgcn_mfma_f32_16x16x32_bf16(a0, b0, acc[0][0], 0, 0, 0);
        acc[0][1] = __builtin_amdgcn_mfma_f32_16x16x32_bf16(a0, b1, acc[0][1], 0, 0, 0);
        acc[0][2] = __builtin_amdgcn_mfma_f32_16x16x32_bf16(a0, b2, acc[0][2], 0, 0, 0);
        acc[0][3] = __builtin_amdgcn_mfma_f32_16x16x32_bf16(a0, b3, acc[0][3], 0, 0, 0);
        acc[1][0] = __builtin_amdgcn_mfma_f32_16x16x32_bf16(a1, b0, acc[1][0], 0, 0, 0);
        acc[1][1] = __builtin_amdgcn_mfma_f32_16x16x32_bf16(a1, b1, acc[1][1], 0, 0, 0);
        acc[1][2] = __builtin_amdgcn_mfma_f32_16x16x32_bf16(a1, b2, acc[1][2], 0, 0, 0);
        acc[1][3] = __builtin_amdgcn_mfma_f32_16x16x32_bf16(a1, b3, acc[1][3], 0, 0, 0);
    }

    // ---- epilogue: scale, diag capture, mask, store rows to LDS ----
    const float invT = 1.0f / 0.07f;
#pragma unroll
    for (int mi = 0; mi < 2; ++mi) {
#pragma unroll
        for (int ni = 0; ni < 4; ++ni) {
            int col = w * 64 + ni * 16 + lr;
            float ci = colInv[col];
            float gv = validF[col];
#pragma unroll
            for (int reg = 0; reg < 4; ++reg) {
                int lrow = mi * 16 + lg * 4 + reg;
                float s = acc[mi][ni][reg] * invT * rowInv[lrow] * ci;
                if (col == nbase + lrow) diagLds[lrow] = s;
                simLds[lrow * SIMP + col] = (gv > 0.5f) ? s : -1e30f;
            }
        }
    }
    __syncthreads();

    // ---- one wave per row: max/argmax + sum-exp via shfl only ----
    for (int k = w; k < MROWS; k += 4) {
        const float* row = &simLds[k * SIMP];
        float v0 = row[l];
        float v1 = row[64 + l];
        float v2 = row[128 + l];
        float v3 = row[192 + l];
        float mv = v0; int mi = l;
        if (v1 > mv) { mv = v1; mi = l + 64; }
        if (v2 > mv) { mv = v2; mi = l + 128; }
        if (v3 > mv) { mv = v3; mi = l + 192; }
#pragma unroll
        for (int off = 32; off > 0; off >>= 1) {
            float ov = __shfl_xor(mv, off, 64);
            int   oi = __shfl_xor(mi, off, 64);
            if (ov > mv || (ov == mv && oi < mi)) { mv = ov; mi = oi; }
        }
        float e = __expf(v0 - mv) + __expf(v1 - mv) + __expf(v2 - mv) + __expf(v3 - mv);
#pragma unroll
        for (int off = 32; off > 0; off >>= 1) e += __shfl_xor(e, off, 64);
        if (l == 0) {
            float vfn = validF[nbase + k];
            float lz = mv + __logf(e);
            rowLoss[k] = (vfn > 0.5f) ? (lz - diagLds[k]) : 0.0f;
            rowCorr[k] = (vfn > 0.5f && mi == nbase + k) ? 1.0f : 0.0f;
        }
    }
    __syncthreads();

    if (t == 0) {
        float la = 0.0f, ca = 0.0f;
#pragma unroll
        for (int k = 0; k < MROWS; ++k) { la += rowLoss[k]; ca += rowCorr[k]; }
        lossPart[(size_t)b * NSTRIP + strip] = la;
        corrPart[(size_t)b * NSTRIP + strip] = ca;
    }
}

// ---------------------------------------------------------------------------
// Kernel C: per-batch include / n_valid logic, final two scalars.
// ---------------------------------------------------------------------------
__global__ __launch_bounds__(256) void finalize_kernel(
        const float* __restrict__ GV,
        const float* __restrict__ lossPart,
        const float* __restrict__ corrPart,
        float* __restrict__ out) {
    __shared__ float sl[BB], sc2[BB], st2[BB];
    int t = threadIdx.x;           // 256 threads: 8 per batch
    int b = t >> 3, s = t & 7;

    float nvp = 0.0f;
    const float4* g4 = reinterpret_cast<const float4*>(GV + (size_t)b * NN);
#pragma unroll
    for (int q = 0; q < 8; ++q) {
        float4 v = g4[s * 8 + q];
        nvp += v.x + v.y + v.z + v.w;
    }
#pragma unroll
    for (int off = 1; off < 8; off <<= 1) nvp += __shfl_xor(nvp, off, 64);

    if (s == 0) {
        float lb = 0.0f, cb = 0.0f;
#pragma unroll
        for (int k = 0; k < NSTRIP; ++k) {
            lb += lossPart[b * NSTRIP + k];
            cb += corrPart[b * NSTRIP + k];
        }
        bool inc = (nvp >= 2.0f);
        sl[b]  = inc ? (lb / fmaxf(nvp, 1.0f)) : 0.0f;
        sc2[b] = inc ? cb : 0.0f;
        st2[b] = inc ? nvp : 0.0f;
    }
    __syncthreads();
    if (t == 0) {
        float L = 0.0f, Ccnt = 0.0f, Tcnt = 0.0f;
        for (int bb = 0; bb < BB; ++bb) { L += sl[bb]; Ccnt += sc2[bb]; Tcnt += st2[bb]; }
        float avg = L / (float)BB;
        out[0] = (Tcnt > 0.0f) ? avg : 0.0f;
        out[1] = (Tcnt > 0.0f) ? (Ccnt / fmaxf(Tcnt, 1.0f) * 100.0f) : 0.0f;
    }
}

extern "C" void kernel_launch(void* const* d_in, const int* in_sizes, int n_in,
                              void* d_out, int out_size, void* d_ws, size_t ws_size,
                              hipStream_t stream) {
    const float* fr = (const float*)d_in[0];  // fmap_rgb
    const float* fd = (const float*)d_in[1];  // fmap_depth
    // d_in[2] = projected_coords: DEAD in reference (_rgb_pos never used)
    const float* vm = (const float*)d_in[3];  // valid_mask

    float* out = (float*)d_out;
    char* ws = (char*)d_ws;

    // Workspace layout (~9.1 MB total)
    size_t featBytes = (size_t)BB * NN * CC * 2;        // 4 MB each (bf16)
    size_t partBytes = (size_t)BB * 16 * NN * 4;        // 512 KB each
    unsigned short* Dbf = (unsigned short*)ws;
    unsigned short* Rbf = (unsigned short*)(ws + featBytes);
    float* nPartD   = (float*)(ws + 2 * featBytes);
    float* nPartR   = (float*)(ws + 2 * featBytes + partBytes);
    float* GV       = (float*)(ws + 2 * featBytes + 2 * partBytes);
    float* lossPart = GV + (size_t)BB * NN;             // BB*NSTRIP
    float* corrPart = lossPart + BB * NSTRIP;           // BB*NSTRIP

    hipLaunchKernelGGL(gather_kernel, dim3(BB * 16), dim3(256), 0, stream,
                       fr, fd, vm, Dbf, Rbf, nPartD, nPartR, GV);
    hipLaunchKernelGGL(sim_loss_kernel, dim3(BB * NSTRIP), dim3(256), 0, stream,
                       Dbf, Rbf, nPartD, nPartR, GV, lossPart, corrPart);
    hipLaunchKernelGGL(finalize_kernel, dim3(1), dim3(256), 0, stream,
                       GV, lossPart, corrPart, out);
}